// Round 13
// baseline (501.954 us; speedup 1.0000x reference)
//
#include <hip/hip_runtime.h>
#include <hip/hip_bf16.h>
#include <math.h>

#define NN 100000      // nodes
#define NE 1600000     // edges
#define IN_DIM 6
#define EDGE_DIM 2
#define HH 5           // heads
#define CC 5           // channels/head
#define DD 25          // hidden = HH*CC
#define DS 32          // padded fp32 row stride (128B rows)
#define INV_SQRT_C 0.4472135954999579f
#define NBUK 200       // coarse dst buckets
#define BUKW 500       // nodes per bucket (200*500 = 100000 exact)
#define KPB 800        // partition blocks
#define CH (NE / KPB)  // 2000 edges per partition block
#define NPB 48         // nodes per block in edge kernel (12 per wave x 4 waves)
#define NBLK ((NN + NPB - 1) / NPB)   // 2084

// q record: 80 B/node (40 shorts). Head h: 16-B chunk at short 40n + 8h = [q0..q4,pad3].
// kv record: 128 B/node (64 shorts), line-aligned. Head h: 16-B chunk at short 64n + 8h
//            = [k0..k4, v0,v1,v2] + 4-B at short 64n + 40 + 2h = [v3,v4].

__device__ __forceinline__ unsigned int f2bf(float f) {   // fp32 -> bf16 bits (RNE)
    unsigned int u = __float_as_uint(f);
    return (u + 0x7fffu + ((u >> 16) & 1u)) >> 16;
}
__device__ __forceinline__ float bflo(unsigned int u) { return __uint_as_float(u << 16); }
__device__ __forceinline__ float bfhi(unsigned int u) { return __uint_as_float(u & 0xffff0000u); }

// ---------------- step 1: per-block bucket counts (no atomics to global) ----------------
__global__ __launch_bounds__(256) void k_cnt(const int* __restrict__ ei, int* __restrict__ cnt) {
    __shared__ int scnt[NBUK];
    int base = blockIdx.x * CH;
    for (int i = threadIdx.x; i < NBUK; i += 256) scnt[i] = 0;
    __syncthreads();
    for (int i = threadIdx.x; i < CH; i += 256)
        atomicAdd(&scnt[ei[NE + base + i] / BUKW], 1);
    __syncthreads();
    for (int i = threadIdx.x; i < NBUK; i += 256)
        cnt[blockIdx.x * NBUK + i] = scnt[i];           // coalesced row write
}

// ---------------- step 2: per-bucket scan over KPB block counts ----------------
__global__ __launch_bounds__(1024) void k_cscan(const int* __restrict__ cnt,
                                                int* __restrict__ off,
                                                int* __restrict__ bucketTot) {
    __shared__ int s[1024];
    int b = blockIdx.x;
    int t = threadIdx.x;
    int v = (t < KPB) ? cnt[t * NBUK + b] : 0;
    s[t] = v;
    __syncthreads();
    for (int o = 1; o < 1024; o <<= 1) {
        int u = (t >= o) ? s[t - o] : 0;
        __syncthreads();
        s[t] += u;
        __syncthreads();
    }
    if (t < KPB) off[b * KPB + t] = s[t] - v;           // exclusive within bucket, coalesced
    if (t == 1023) bucketTot[b] = s[1023];
}

// ---------------- step 3: bucket base scan (1 block) ----------------
__global__ void k_bscan(const int* __restrict__ bucketTot, int* __restrict__ bucketBase) {
    __shared__ int s[256];
    int t = threadIdx.x;
    int v = (t < NBUK) ? bucketTot[t] : 0;
    s[t] = v;
    __syncthreads();
    for (int o = 1; o < 256; o <<= 1) {
        int u = (t >= o) ? s[t - o] : 0;
        __syncthreads();
        s[t] += u;
        __syncthreads();
    }
    if (t < NBUK) bucketBase[t] = s[t] - v;             // exclusive
}

// ---------------- step 4: write records to exact dense bucket-grouped positions ----------------
__global__ __launch_bounds__(256) void k_part2(const int* __restrict__ ei,
                                               const float* __restrict__ ea,
                                               const int* __restrict__ off,
                                               const int* __restrict__ bucketBase,
                                               uint2* __restrict__ stage) {
    __shared__ int sdst[CH];        // 8 KB
    __shared__ int sbase[NBUK];
    __shared__ int swp[NBUK];
    int blk = blockIdx.x;
    int base = blk * CH;
    for (int i = threadIdx.x; i < NBUK; i += 256) {
        sbase[i] = bucketBase[i] + off[i * KPB + blk];
        swp[i] = 0;
    }
    for (int i = threadIdx.x; i < CH; i += 256) sdst[i] = ei[NE + base + i];
    __syncthreads();
    for (int i = threadIdx.x; i < CH; i += 256) {
        int dst = sdst[i];
        int b = dst / BUKW;
        int src = ei[base + i];
        float2 eav = ((const float2*)ea)[base + i];
        int p = sbase[b] + atomicAdd(&swp[b], 1);       // LDS rank only
        uint2 r;
        r.x = (unsigned)src | ((unsigned)(dst - b * BUKW) << 17);  // src:17b, dstLocal:9b
        r.y = f2bf(eav.x) | (f2bf(eav.y) << 16);
        stage[p] = r;
    }
}

// ---------------- step 5: per-bucket node hist + scan + rowptr + place + degree-bin hist ---------
__global__ __launch_bounds__(512) void k_place(const int* __restrict__ bucketTot,
                                               const int* __restrict__ bucketBase,
                                               const uint2* __restrict__ stage,
                                               int* __restrict__ rowptr,
                                               uint2* __restrict__ csr,
                                               int* __restrict__ dbh) {
    __shared__ int hist[BUKW];
    __shared__ int cur[BUKW];
    __shared__ int s[512];
    __shared__ int lh[256];
    int b = blockIdx.x;
    int t = threadIdx.x;
    int node0 = b * BUKW;
    int begin = b == 0 ? 0 : 0;   // dense: begin = bucketBase[b]
    begin = bucketBase[b];
    int cnt = bucketTot[b];
    for (int i = t; i < BUKW; i += 512) hist[i] = 0;
    if (t < 256) lh[t] = 0;
    __syncthreads();
    for (int i = t; i < cnt; i += 512) {
        uint2 r = stage[begin + i];
        atomicAdd(&hist[r.x >> 17], 1);
    }
    __syncthreads();
    int hv = (t < BUKW) ? hist[t] : 0;
    s[t] = hv;
    __syncthreads();
    for (int o = 1; o < 512; o <<= 1) {
        int u = (t >= o) ? s[t - o] : 0;
        __syncthreads();
        s[t] += u;
        __syncthreads();
    }
    if (t < BUKW) {
        int o = begin + s[t] - hv;
        rowptr[node0 + t] = o;
        cur[t] = o;
        atomicAdd(&lh[hv > 255 ? 255 : hv], 1);          // degree-bin histogram (LDS)
    }
    if (b == NBUK - 1 && t == 0) rowptr[NN] = NE;
    __syncthreads();
    if (t < 256) dbh[b * 256 + t] = lh[t];               // coalesced column write
    for (int i = t; i < cnt; i += 512) {
        uint2 r = stage[begin + i];                      // L2 hit (just streamed)
        int dl = (int)(r.x >> 17);
        int p = atomicAdd(&cur[dl], 1);
        uint2 o;
        o.x = r.x & 0x1FFFFu;
        o.y = r.y;
        csr[p] = o;
    }
}

// ---------------- degree sort: per-bin scan over buckets; bin-offset scan; place ----------------
__global__ void k_ds(const int* __restrict__ dbh, int* __restrict__ dbhE,
                     int* __restrict__ binTot) {
    __shared__ int s[256];
    int bin = blockIdx.x;
    int t = threadIdx.x;
    int v = (t < NBUK) ? dbh[t * 256 + bin] : 0;
    s[t] = v;
    __syncthreads();
    for (int o = 1; o < 256; o <<= 1) {
        int u = (t >= o) ? s[t - o] : 0;
        __syncthreads();
        s[t] += u;
        __syncthreads();
    }
    if (t < NBUK) dbhE[bin * NBUK + t] = s[t] - v;       // exclusive within bin, coalesced
    if (t == 255) binTot[bin] = s[255];
}

__global__ void k_ds2(const int* __restrict__ binTot, int* __restrict__ binOff) {
    __shared__ int s[256];
    int t = threadIdx.x;
    int v = binTot[t];
    s[t] = v;
    __syncthreads();
    for (int o = 1; o < 256; o <<= 1) {
        int u = (t >= o) ? s[t - o] : 0;
        __syncthreads();
        s[t] += u;
        __syncthreads();
    }
    binOff[t] = s[t] - v;
}

__global__ __launch_bounds__(512) void k_dp(const int* __restrict__ rowptr,
                                            const int* __restrict__ dbhE,
                                            const int* __restrict__ binOff,
                                            int* __restrict__ perm,
                                            uint2* __restrict__ begend) {
    __shared__ int lcur[256];
    int b = blockIdx.x;
    int t = threadIdx.x;
    if (t < 256) lcur[t] = 0;
    __syncthreads();
    if (t < BUKW) {
        int node = b * BUKW + t;
        int beg = rowptr[node], end = rowptr[node + 1];
        int d = end - beg;
        if (d > 255) d = 255;
        int r = atomicAdd(&lcur[d], 1);
        int pos = binOff[d] + dbhE[d * NBUK + b] + r;
        int slot = NN - 1 - pos;                          // descending: heavy first
        perm[slot] = node;
        begend[slot] = make_uint2((unsigned)beg, (unsigned)end);
    }
}

// ------- per-layer node pass: q (80-B rows), kv (128-B rows), skip fp32; l0 fuses input proj -----
__global__ void k_qkv_skip(const float* __restrict__ h,
                           const float* __restrict__ x, const float* __restrict__ WiC,
                           const float* __restrict__ biC, int use_x,
                           const float* __restrict__ Wq, const float* __restrict__ bq,
                           const float* __restrict__ Wk, const float* __restrict__ bk,
                           const float* __restrict__ Wv, const float* __restrict__ bv,
                           const float* __restrict__ Ws, const float* __restrict__ bs,
                           __hip_bfloat16* __restrict__ q, __hip_bfloat16* __restrict__ kv,
                           float* __restrict__ hout) {
    __shared__ float sWq[DD * DD], sWk[DD * DD], sWv[DD * DD], sWs[DD * DD];
    __shared__ float sWi[IN_DIM * DD];
    __shared__ float sb[4 * DD];
    __shared__ float sbi[DD];
    for (int i = threadIdx.x; i < DD * DD; i += blockDim.x) {
        sWq[i] = Wq[i]; sWk[i] = Wk[i]; sWv[i] = Wv[i]; sWs[i] = Ws[i];
    }
    if (use_x && threadIdx.x < IN_DIM * DD) sWi[threadIdx.x] = WiC[threadIdx.x];
    if (threadIdx.x < DD) {
        sb[threadIdx.x]          = bq[threadIdx.x];
        sb[DD + threadIdx.x]     = bk[threadIdx.x];
        sb[2 * DD + threadIdx.x] = bv[threadIdx.x];
        sb[3 * DD + threadIdx.x] = bs[threadIdx.x];
        if (use_x) sbi[threadIdx.x] = biC[threadIdx.x];
    }
    __syncthreads();
    int tid = blockIdx.x * blockDim.x + threadIdx.x;
    int n = tid / DD, d = tid - n * DD;
    if (n >= NN) return;
    float aq = sb[d], ak = sb[DD + d], av = sb[2 * DD + d], asv = sb[3 * DD + d];
    float xr[IN_DIM];
    const float* hr = h + (size_t)n * DS;
    if (use_x) {
        const float* xp = x + (size_t)n * IN_DIM;
#pragma unroll
        for (int j = 0; j < IN_DIM; j++) xr[j] = xp[j];
    }
#pragma unroll
    for (int i = 0; i < DD; i++) {
        float hv;
        if (use_x) {
            hv = sbi[i];
#pragma unroll
            for (int j = 0; j < IN_DIM; j++) hv += xr[j] * sWi[j * DD + i];
        } else {
            hv = hr[i];
        }
        aq  += hv * sWq[i * DD + d];
        ak  += hv * sWk[i * DD + d];
        av  += hv * sWv[i * DD + d];
        asv += hv * sWs[i * DD + d];
    }
    int h5 = d / 5, c5 = d - 5 * h5;
    q[(size_t)n * 40 + 8 * h5 + c5] = __float2bfloat16(aq * INV_SQRT_C);  // fold 1/sqrt(C)
    size_t rb = (size_t)n * 64;      // 128-B rows
    kv[rb + 8 * h5 + c5] = __float2bfloat16(ak);                          // k0..k4
    if (c5 < 3) kv[rb + 8 * h5 + 5 + c5] = __float2bfloat16(av);          // v0..v2
    else        kv[rb + 40 + 2 * h5 + (c5 - 3)] = __float2bfloat16(av);   // v3,v4
    hout[(size_t)n * DS + d] = asv;
}

// ---------------- fused edge pass: 5 lanes = 5 heads/node, desc-degree-sorted, 4-way unroll ------
struct EState { float l, Sx, Sy, a0, a1, a2, a3, a4; };

__device__ __forceinline__ void edge_acc(EState& st, uint2 rec, uint4 A, unsigned int B,
                                         float qa0, float qa1, float qa2, float qa3, float qa4,
                                         float qwx, float qwy) {
    float eax = bflo(rec.y), eay = bfhi(rec.y);
    float k0 = bflo(A.x), k1 = bfhi(A.x), k2 = bflo(A.y), k3 = bfhi(A.y), k4 = bflo(A.z);
    float v0 = bfhi(A.z), v1 = bflo(A.w), v2 = bfhi(A.w), v3 = bflo(B), v4 = bfhi(B);
    float s = qa0 * k0 + qa1 * k1 + qa2 * k2 + qa3 * k3 + qa4 * k4 + eax * qwx + eay * qwy;
    float cf = __expf(s);
    st.l += cf; st.Sx += cf * eax; st.Sy += cf * eay;
    st.a0 += cf * v0; st.a1 += cf * v1; st.a2 += cf * v2; st.a3 += cf * v3; st.a4 += cf * v4;
}

__global__ __launch_bounds__(256) void k_edge_fused(
    const uint2* __restrict__ begend, const uint2* __restrict__ csr,
    const int* __restrict__ perm,
    const float* __restrict__ We, const __hip_bfloat16* __restrict__ q,
    const __hip_bfloat16* __restrict__ kv, float* __restrict__ hout,
    int fuse_head, const float* __restrict__ Wo, const float* __restrict__ bo,
    float* __restrict__ out) {
    __shared__ float sWe[EDGE_DIM * DD];
    __shared__ float sWo[DD];
    __shared__ float sbo;
    if (threadIdx.x < EDGE_DIM * DD) sWe[threadIdx.x] = We[threadIdx.x];
    if (threadIdx.x < DD) sWo[threadIdx.x] = Wo[threadIdx.x];
    if (threadIdx.x == 0) sbo = bo[0];
    __syncthreads();
    int lane = threadIdx.x & 63;
    int wv   = threadIdx.x >> 6;
    int grp  = lane / 5;             // 0..12 (12 = idle lanes 60-63)
    int h    = lane - grp * 5;       // head
    int idx  = blockIdx.x * NPB + wv * 12 + grp;
    bool act = (grp < 12) && (idx < NN);
    int node = 0;

    int beg = 0, end = 0;
    float qa0 = 0, qa1 = 0, qa2 = 0, qa3 = 0, qa4 = 0, qwx = 0, qwy = 0;
    if (act) {
        node = perm[idx];
        uint2 be = begend[idx];                           // coalesced
        beg = (int)be.x; end = (int)be.y;
        uint4 qc = *(const uint4*)(q + (size_t)node * 40 + 8 * h);  // 16-B aligned
        qa0 = bflo(qc.x); qa1 = bfhi(qc.x); qa2 = bflo(qc.y); qa3 = bfhi(qc.y); qa4 = bflo(qc.z);
        const float* wx = &sWe[5 * h];
        const float* wy = &sWe[DD + 5 * h];
        qwx = qa0 * wx[0] + qa1 * wx[1] + qa2 * wx[2] + qa3 * wx[3] + qa4 * wx[4];
        qwy = qa0 * wy[0] + qa1 * wy[1] + qa2 * wy[2] + qa3 * wy[3] + qa4 * wy[4];
    }

    EState st = {0.f, 0.f, 0.f, 0.f, 0.f, 0.f, 0.f, 0.f};

    int p = beg;
    for (; p + 4 <= end; p += 4) {           // 4 independent gathers in flight
        uint2 r0 = csr[p], r1 = csr[p + 1], r2 = csr[p + 2], r3 = csr[p + 3];
        const __hip_bfloat16* b0 = kv + ((size_t)r0.x << 6);
        const __hip_bfloat16* b1 = kv + ((size_t)r1.x << 6);
        const __hip_bfloat16* b2 = kv + ((size_t)r2.x << 6);
        const __hip_bfloat16* b3 = kv + ((size_t)r3.x << 6);
        uint4 A0 = *(const uint4*)(b0 + 8 * h);
        uint4 A1 = *(const uint4*)(b1 + 8 * h);
        uint4 A2 = *(const uint4*)(b2 + 8 * h);
        uint4 A3 = *(const uint4*)(b3 + 8 * h);
        unsigned int B0 = *(const unsigned int*)(b0 + 40 + 2 * h);
        unsigned int B1 = *(const unsigned int*)(b1 + 40 + 2 * h);
        unsigned int B2 = *(const unsigned int*)(b2 + 40 + 2 * h);
        unsigned int B3 = *(const unsigned int*)(b3 + 40 + 2 * h);
        edge_acc(st, r0, A0, B0, qa0, qa1, qa2, qa3, qa4, qwx, qwy);
        edge_acc(st, r1, A1, B1, qa0, qa1, qa2, qa3, qa4, qwx, qwy);
        edge_acc(st, r2, A2, B2, qa0, qa1, qa2, qa3, qa4, qwx, qwy);
        edge_acc(st, r3, A3, B3, qa0, qa1, qa2, qa3, qa4, qwx, qwy);
    }
    for (; p < end; ++p) {
        uint2 r0 = csr[p];
        const __hip_bfloat16* b0 = kv + ((size_t)r0.x << 6);
        uint4 A0 = *(const uint4*)(b0 + 8 * h);
        unsigned int B0 = *(const unsigned int*)(b0 + 40 + 2 * h);
        edge_acc(st, r0, A0, B0, qa0, qa1, qa2, qa3, qa4, qwx, qwy);
    }

    float dot = 0.f;
    if (act) {
        float inv = 1.0f / (st.l + 1e-16f);
        const float* wx = &sWe[5 * h];
        const float* wy = &sWe[DD + 5 * h];
        float* ho = hout + (size_t)node * DS + 5 * h;
        float n0 = ho[0] + (st.a0 + st.Sx * wx[0] + st.Sy * wy[0]) * inv;
        float n1 = ho[1] + (st.a1 + st.Sx * wx[1] + st.Sy * wy[1]) * inv;
        float n2 = ho[2] + (st.a2 + st.Sx * wx[2] + st.Sy * wy[2]) * inv;
        float n3 = ho[3] + (st.a3 + st.Sx * wx[3] + st.Sy * wy[3]) * inv;
        float n4 = ho[4] + (st.a4 + st.Sx * wx[4] + st.Sy * wy[4]) * inv;
        ho[0] = n0; ho[1] = n1; ho[2] = n2; ho[3] = n3; ho[4] = n4;
        if (fuse_head) {
            const float* wo = &sWo[5 * h];
            dot = n0 * wo[0] + n1 * wo[1] + n2 * wo[2] + n3 * wo[3] + n4 * wo[4];
        }
    }
    if (fuse_head) {
        float dsum = dot;
#pragma unroll
        for (int k = 1; k < 5; k++) dsum += __shfl(dot, (grp * 5 + k) & 63, 64);
        if (act && h == 0) out[node] = 1.0f / (1.0f + __expf(-(dsum + sbo)));
    }
}

extern "C" void kernel_launch(void* const* d_in, const int* in_sizes, int n_in,
                              void* d_out, int out_size, void* d_ws, size_t ws_size,
                              hipStream_t stream) {
    const float* x     = (const float*)d_in[0];
    const int*   ei    = (const int*)d_in[1];     // [2,E]: src=[0..E), dst=[E..2E)
    const float* ea    = (const float*)d_in[2];   // [E,2]
    const float* Wi    = (const float*)d_in[3];
    const float* bi    = (const float*)d_in[4];
    const float* Wq    = (const float*)d_in[5];
    const float* bq    = (const float*)d_in[6];
    const float* Wk    = (const float*)d_in[7];
    const float* bk    = (const float*)d_in[8];
    const float* Wv    = (const float*)d_in[9];
    const float* bv    = (const float*)d_in[10];
    const float* We    = (const float*)d_in[11];
    const float* Wskip = (const float*)d_in[12];
    const float* bskip = (const float*)d_in[13];
    const float* Wo    = (const float*)d_in[14];
    const float* bo    = (const float*)d_in[15];
    float* out = (float*)d_out;
    (void)in_sizes; (void)n_in; (void)out_size; (void)ws_size;

    char* wsb = (char*)d_ws;
    size_t off0 = 0;
    auto alloc = [&](size_t bytes) {
        void* p = wsb + off0;
        off0 += (bytes + 127) & ~(size_t)127;
        return p;
    };
    uint2* stage  = (uint2*)alloc((size_t)NE * sizeof(uint2));               // 12.8 MB
    uint2* csr    = (uint2*)alloc((size_t)NE * sizeof(uint2));               // 12.8 MB
    __hip_bfloat16* kvrec = (__hip_bfloat16*)alloc((size_t)NN * 64 * 2);     // 12.8 MB
    __hip_bfloat16* qrec  = (__hip_bfloat16*)alloc((size_t)NN * 40 * 2);     // 8 MB
    float* hA     = (float*)alloc((size_t)NN * DS * sizeof(float));
    float* hB     = (float*)alloc((size_t)NN * DS * sizeof(float));
    int*   rowptr = (int*)alloc((size_t)(NN + 1) * sizeof(int));
    int*   cnt    = (int*)alloc((size_t)KPB * NBUK * sizeof(int));           // 640 KB
    int*   offm   = (int*)alloc((size_t)NBUK * KPB * sizeof(int));           // 640 KB
    int*   bucketTot  = (int*)alloc(NBUK * sizeof(int));
    int*   bucketBase = (int*)alloc(NBUK * sizeof(int));
    int*   dbh    = (int*)alloc((size_t)NBUK * 256 * sizeof(int));           // 200 KB
    int*   dbhE   = (int*)alloc((size_t)256 * NBUK * sizeof(int));           // 200 KB
    int*   binTot = (int*)alloc(256 * sizeof(int));
    int*   binOff = (int*)alloc(256 * sizeof(int));
    int*   perm   = (int*)alloc((size_t)NN * sizeof(int));
    uint2* begend = (uint2*)alloc((size_t)NN * sizeof(uint2));               // 800 KB

    dim3 blk(256);
    int gND = (NN * DD + 255) / 256;    // 9766

    // atomic-free CSR build + degree sort (every call — ws is re-poisoned)
    k_cnt<<<KPB, blk, 0, stream>>>(ei, cnt);
    k_cscan<<<NBUK, dim3(1024), 0, stream>>>(cnt, offm, bucketTot);
    k_bscan<<<1, blk, 0, stream>>>(bucketTot, bucketBase);
    k_part2<<<KPB, blk, 0, stream>>>(ei, ea, offm, bucketBase, stage);
    k_place<<<NBUK, dim3(512), 0, stream>>>(bucketTot, bucketBase, stage, rowptr, csr, dbh);
    k_ds<<<256, blk, 0, stream>>>(dbh, dbhE, binTot);
    k_ds2<<<1, blk, 0, stream>>>(binTot, binOff);
    k_dp<<<NBUK, dim3(512), 0, stream>>>(rowptr, dbhE, binOff, perm, begend);

    float* hc = hA;
    float* hn = hB;
    for (int l = 0; l < 3; l++) {
        k_qkv_skip<<<gND, blk, 0, stream>>>(hc, x, Wi, bi, (l == 0) ? 1 : 0,
                                            Wq + (size_t)l * DD * DD, bq + (size_t)l * DD,
                                            Wk + (size_t)l * DD * DD, bk + (size_t)l * DD,
                                            Wv + (size_t)l * DD * DD, bv + (size_t)l * DD,
                                            Wskip + (size_t)l * DD * DD, bskip + (size_t)l * DD,
                                            qrec, kvrec, hn);
        k_edge_fused<<<NBLK, blk, 0, stream>>>(begend, csr, perm,
                                               We + (size_t)l * EDGE_DIM * DD,
                                               qrec, kvrec, hn,
                                               (l == 2) ? 1 : 0, Wo, bo, out);
        float* t = hc; hc = hn; hn = t;
    }
}

// Round 14
// 351.367 us; speedup vs baseline: 1.4286x; 1.4286x over previous
//
#include <hip/hip_runtime.h>
#include <hip/hip_bf16.h>
#include <math.h>

#define NN 100000      // nodes
#define NE 1600000     // edges
#define IN_DIM 6
#define EDGE_DIM 2
#define HH 5           // heads
#define CC 5           // channels/head
#define DD 25          // hidden = HH*CC
#define DS 32          // padded fp32 row stride (128B rows)
#define INV_SQRT_C 0.4472135954999579f
#define NBUK 200       // coarse dst buckets
#define BUKW 500       // nodes per bucket (200*500 = 100000 exact)
#define KPB 800        // partition blocks
#define CH (NE / KPB)  // 2000 edges per partition block
#define NPB 48         // nodes per block in edge kernel (12 per wave x 4 waves)
#define NBLK ((NN + NPB - 1) / NPB)   // 2084

// q record: 80 B/node (40 shorts). Head h: 16-B chunk at short 40n + 8h = [q0..q4,pad3].
// kv record: 128 B/node (64 shorts), line-aligned. Head h: 16-B chunk at short 64n + 8h
//            = [k0..k4, v0,v1,v2] + 4-B at short 64n + 40 + 2h = [v3,v4].

__device__ __forceinline__ unsigned int f2bf(float f) {   // fp32 -> bf16 bits (RNE)
    unsigned int u = __float_as_uint(f);
    return (u + 0x7fffu + ((u >> 16) & 1u)) >> 16;
}
__device__ __forceinline__ float bflo(unsigned int u) { return __uint_as_float(u << 16); }
__device__ __forceinline__ float bfhi(unsigned int u) { return __uint_as_float(u & 0xffff0000u); }

// ---------------- step 1: per-block bucket counts (no atomics to global) ----------------
__global__ __launch_bounds__(256) void k_cnt(const int* __restrict__ ei, int* __restrict__ cnt) {
    __shared__ int scnt[NBUK];
    int base = blockIdx.x * CH;
    for (int i = threadIdx.x; i < NBUK; i += 256) scnt[i] = 0;
    __syncthreads();
    for (int i = threadIdx.x; i < CH; i += 256)
        atomicAdd(&scnt[ei[NE + base + i] / BUKW], 1);
    __syncthreads();
    for (int i = threadIdx.x; i < NBUK; i += 256)
        cnt[blockIdx.x * NBUK + i] = scnt[i];           // coalesced row write
}

// ---------------- step 2: per-bucket scan over KPB block counts ----------------
__global__ __launch_bounds__(1024) void k_cscan(const int* __restrict__ cnt,
                                                int* __restrict__ off,
                                                int* __restrict__ bucketTot) {
    __shared__ int s[1024];
    int b = blockIdx.x;
    int t = threadIdx.x;
    int v = (t < KPB) ? cnt[t * NBUK + b] : 0;
    s[t] = v;
    __syncthreads();
    for (int o = 1; o < 1024; o <<= 1) {
        int u = (t >= o) ? s[t - o] : 0;
        __syncthreads();
        s[t] += u;
        __syncthreads();
    }
    if (t < KPB) off[b * KPB + t] = s[t] - v;           // exclusive within bucket, coalesced
    if (t == 1023) bucketTot[b] = s[1023];
}

// ---------------- step 3: bucket base scan (1 block) ----------------
__global__ void k_bscan(const int* __restrict__ bucketTot, int* __restrict__ bucketBase) {
    __shared__ int s[256];
    int t = threadIdx.x;
    int v = (t < NBUK) ? bucketTot[t] : 0;
    s[t] = v;
    __syncthreads();
    for (int o = 1; o < 256; o <<= 1) {
        int u = (t >= o) ? s[t - o] : 0;
        __syncthreads();
        s[t] += u;
        __syncthreads();
    }
    if (t < NBUK) bucketBase[t] = s[t] - v;             // exclusive
}

// ---------------- step 4: write records to exact dense bucket-grouped positions ----------------
__global__ __launch_bounds__(256) void k_part2(const int* __restrict__ ei,
                                               const float* __restrict__ ea,
                                               const int* __restrict__ off,
                                               const int* __restrict__ bucketBase,
                                               uint2* __restrict__ stage) {
    __shared__ int sdst[CH];        // 8 KB
    __shared__ int sbase[NBUK];
    __shared__ int swp[NBUK];
    int blk = blockIdx.x;
    int base = blk * CH;
    for (int i = threadIdx.x; i < NBUK; i += 256) {
        sbase[i] = bucketBase[i] + off[i * KPB + blk];
        swp[i] = 0;
    }
    for (int i = threadIdx.x; i < CH; i += 256) sdst[i] = ei[NE + base + i];
    __syncthreads();
    for (int i = threadIdx.x; i < CH; i += 256) {
        int dst = sdst[i];
        int b = dst / BUKW;
        int src = ei[base + i];
        float2 eav = ((const float2*)ea)[base + i];
        int p = sbase[b] + atomicAdd(&swp[b], 1);       // LDS rank only
        uint2 r;
        r.x = (unsigned)src | ((unsigned)(dst - b * BUKW) << 17);  // src:17b, dstLocal:9b
        r.y = f2bf(eav.x) | (f2bf(eav.y) << 16);
        stage[p] = r;
    }
}

// ---------------- step 5: per-bucket node hist + scan + rowptr + place + degree-bin hist ---------
__global__ __launch_bounds__(512) void k_place(const int* __restrict__ bucketTot,
                                               const int* __restrict__ bucketBase,
                                               const uint2* __restrict__ stage,
                                               int* __restrict__ rowptr,
                                               uint2* __restrict__ csr,
                                               int* __restrict__ dbh) {
    __shared__ int hist[BUKW];
    __shared__ int cur[BUKW];
    __shared__ int s[512];
    __shared__ int lh[256];
    int b = blockIdx.x;
    int t = threadIdx.x;
    int node0 = b * BUKW;
    int begin = bucketBase[b];
    int cnt = bucketTot[b];
    for (int i = t; i < BUKW; i += 512) hist[i] = 0;
    if (t < 256) lh[t] = 0;
    __syncthreads();
    for (int i = t; i < cnt; i += 512) {
        uint2 r = stage[begin + i];
        atomicAdd(&hist[r.x >> 17], 1);
    }
    __syncthreads();
    int hv = (t < BUKW) ? hist[t] : 0;
    s[t] = hv;
    __syncthreads();
    for (int o = 1; o < 512; o <<= 1) {
        int u = (t >= o) ? s[t - o] : 0;
        __syncthreads();
        s[t] += u;
        __syncthreads();
    }
    if (t < BUKW) {
        int o = begin + s[t] - hv;
        rowptr[node0 + t] = o;
        cur[t] = o;
        atomicAdd(&lh[hv > 255 ? 255 : hv], 1);          // degree-bin histogram (LDS)
    }
    if (b == NBUK - 1 && t == 0) rowptr[NN] = NE;
    __syncthreads();
    if (t < 256) dbh[b * 256 + t] = lh[t];               // coalesced row write
    for (int i = t; i < cnt; i += 512) {
        uint2 r = stage[begin + i];                      // L2 hit (just streamed)
        int dl = (int)(r.x >> 17);
        int p = atomicAdd(&cur[dl], 1);
        uint2 o;
        o.x = r.x & 0x1FFFFu;
        o.y = r.y;
        csr[p] = o;
    }
}

// ---------------- degree sort: per-bin scan over buckets; bin-offset scan; place ----------------
__global__ void k_ds(const int* __restrict__ dbh, int* __restrict__ dbhE,
                     int* __restrict__ binTot) {
    __shared__ int s[256];
    int bin = blockIdx.x;
    int t = threadIdx.x;
    int v = (t < NBUK) ? dbh[t * 256 + bin] : 0;
    s[t] = v;
    __syncthreads();
    for (int o = 1; o < 256; o <<= 1) {
        int u = (t >= o) ? s[t - o] : 0;
        __syncthreads();
        s[t] += u;
        __syncthreads();
    }
    if (t < NBUK) dbhE[bin * NBUK + t] = s[t] - v;       // exclusive within bin, coalesced
    if (t == 255) binTot[bin] = s[255];
}

__global__ void k_ds2(const int* __restrict__ binTot, int* __restrict__ binOff) {
    __shared__ int s[256];
    int t = threadIdx.x;
    int v = binTot[t];
    s[t] = v;
    __syncthreads();
    for (int o = 1; o < 256; o <<= 1) {
        int u = (t >= o) ? s[t - o] : 0;
        __syncthreads();
        s[t] += u;
        __syncthreads();
    }
    binOff[t] = s[t] - v;
}

__global__ __launch_bounds__(512) void k_dp(const int* __restrict__ rowptr,
                                            const int* __restrict__ dbhE,
                                            const int* __restrict__ binOff,
                                            int* __restrict__ perm,
                                            uint2* __restrict__ begend) {
    __shared__ int lcur[256];
    int b = blockIdx.x;
    int t = threadIdx.x;
    if (t < 256) lcur[t] = 0;
    __syncthreads();
    if (t < BUKW) {
        int node = b * BUKW + t;
        int beg = rowptr[node], end = rowptr[node + 1];
        int d = end - beg;
        if (d > 255) d = 255;
        int r = atomicAdd(&lcur[d], 1);
        int pos = binOff[d] + dbhE[d * NBUK + b] + r;
        int slot = NN - 1 - pos;                          // descending: heavy first
        perm[slot] = node;
        begend[slot] = make_uint2((unsigned)beg, (unsigned)end);
    }
}

// ---------------- input projection ----------------
__global__ void k_input_proj(const float* __restrict__ x, const float* __restrict__ Wi,
                             const float* __restrict__ bi, float* __restrict__ h) {
    __shared__ float sW[IN_DIM * DD];
    __shared__ float sb[DD];
    int t = threadIdx.x;
    if (t < IN_DIM * DD) sW[t] = Wi[t];
    if (t < DD) sb[t] = bi[t];
    __syncthreads();
    int tid = blockIdx.x * blockDim.x + t;
    int n = tid / DD, d = tid - n * DD;
    if (n >= NN) return;
    float acc = sb[d];
    const float* xr = x + n * IN_DIM;
#pragma unroll
    for (int i = 0; i < IN_DIM; i++) acc += xr[i] * sW[i * DD + d];
    h[n * DS + d] = acc;
}

// ------- per-layer node pass: q (80-B rows), kv (128-B aligned rows), skip in fp32 -------
__global__ void k_qkv_skip(const float* __restrict__ h,
                           const float* __restrict__ Wq, const float* __restrict__ bq,
                           const float* __restrict__ Wk, const float* __restrict__ bk,
                           const float* __restrict__ Wv, const float* __restrict__ bv,
                           const float* __restrict__ Ws, const float* __restrict__ bs,
                           __hip_bfloat16* __restrict__ q, __hip_bfloat16* __restrict__ kv,
                           float* __restrict__ hout) {
    __shared__ float sWq[DD * DD], sWk[DD * DD], sWv[DD * DD], sWs[DD * DD];
    __shared__ float sb[4 * DD];
    for (int i = threadIdx.x; i < DD * DD; i += blockDim.x) {
        sWq[i] = Wq[i]; sWk[i] = Wk[i]; sWv[i] = Wv[i]; sWs[i] = Ws[i];
    }
    if (threadIdx.x < DD) {
        sb[threadIdx.x]          = bq[threadIdx.x];
        sb[DD + threadIdx.x]     = bk[threadIdx.x];
        sb[2 * DD + threadIdx.x] = bv[threadIdx.x];
        sb[3 * DD + threadIdx.x] = bs[threadIdx.x];
    }
    __syncthreads();
    int tid = blockIdx.x * blockDim.x + threadIdx.x;
    int n = tid / DD, d = tid - n * DD;
    if (n >= NN) return;
    float aq = sb[d], ak = sb[DD + d], av = sb[2 * DD + d], asv = sb[3 * DD + d];
    const float* hr = h + (size_t)n * DS;
#pragma unroll
    for (int i = 0; i < DD; i++) {
        float hv = hr[i];
        aq  += hv * sWq[i * DD + d];
        ak  += hv * sWk[i * DD + d];
        av  += hv * sWv[i * DD + d];
        asv += hv * sWs[i * DD + d];
    }
    int h5 = d / 5, c5 = d - 5 * h5;
    q[(size_t)n * 40 + 8 * h5 + c5] = __float2bfloat16(aq * INV_SQRT_C);  // fold 1/sqrt(C)
    size_t rb = (size_t)n * 64;      // 128-B rows
    kv[rb + 8 * h5 + c5] = __float2bfloat16(ak);                          // k0..k4
    if (c5 < 3) kv[rb + 8 * h5 + 5 + c5] = __float2bfloat16(av);          // v0..v2
    else        kv[rb + 40 + 2 * h5 + (c5 - 3)] = __float2bfloat16(av);   // v3,v4
    hout[(size_t)n * DS + d] = asv;
}

// ---------------- fused edge pass: 5 lanes = 5 heads/node, desc-degree-sorted, 4-way unroll ------
struct EState { float l, Sx, Sy, a0, a1, a2, a3, a4; };

__device__ __forceinline__ void edge_acc(EState& st, uint2 rec, uint4 A, unsigned int B,
                                         float qa0, float qa1, float qa2, float qa3, float qa4,
                                         float qwx, float qwy) {
    float eax = bflo(rec.y), eay = bfhi(rec.y);
    float k0 = bflo(A.x), k1 = bfhi(A.x), k2 = bflo(A.y), k3 = bfhi(A.y), k4 = bflo(A.z);
    float v0 = bfhi(A.z), v1 = bflo(A.w), v2 = bfhi(A.w), v3 = bflo(B), v4 = bfhi(B);
    float s = qa0 * k0 + qa1 * k1 + qa2 * k2 + qa3 * k3 + qa4 * k4 + eax * qwx + eay * qwy;
    float cf = __expf(s);
    st.l += cf; st.Sx += cf * eax; st.Sy += cf * eay;
    st.a0 += cf * v0; st.a1 += cf * v1; st.a2 += cf * v2; st.a3 += cf * v3; st.a4 += cf * v4;
}

__global__ __launch_bounds__(256) void k_edge_fused(
    const uint2* __restrict__ begend, const uint2* __restrict__ csr,
    const int* __restrict__ perm,
    const float* __restrict__ We, const __hip_bfloat16* __restrict__ q,
    const __hip_bfloat16* __restrict__ kv, float* __restrict__ hout,
    int fuse_head, const float* __restrict__ Wo, const float* __restrict__ bo,
    float* __restrict__ out) {
    __shared__ float sWe[EDGE_DIM * DD];
    __shared__ float sWo[DD];
    __shared__ float sbo;
    if (threadIdx.x < EDGE_DIM * DD) sWe[threadIdx.x] = We[threadIdx.x];
    if (threadIdx.x < DD) sWo[threadIdx.x] = Wo[threadIdx.x];
    if (threadIdx.x == 0) sbo = bo[0];
    __syncthreads();
    int lane = threadIdx.x & 63;
    int wv   = threadIdx.x >> 6;
    int grp  = lane / 5;             // 0..12 (12 = idle lanes 60-63)
    int h    = lane - grp * 5;       // head
    int idx  = blockIdx.x * NPB + wv * 12 + grp;
    bool act = (grp < 12) && (idx < NN);
    int node = 0;

    int beg = 0, end = 0;
    float qa0 = 0, qa1 = 0, qa2 = 0, qa3 = 0, qa4 = 0, qwx = 0, qwy = 0;
    if (act) {
        node = perm[idx];
        uint2 be = begend[idx];                           // coalesced
        beg = (int)be.x; end = (int)be.y;
        uint4 qc = *(const uint4*)(q + (size_t)node * 40 + 8 * h);  // 16-B aligned
        qa0 = bflo(qc.x); qa1 = bfhi(qc.x); qa2 = bflo(qc.y); qa3 = bfhi(qc.y); qa4 = bflo(qc.z);
        const float* wx = &sWe[5 * h];
        const float* wy = &sWe[DD + 5 * h];
        qwx = qa0 * wx[0] + qa1 * wx[1] + qa2 * wx[2] + qa3 * wx[3] + qa4 * wx[4];
        qwy = qa0 * wy[0] + qa1 * wy[1] + qa2 * wy[2] + qa3 * wy[3] + qa4 * wy[4];
    }

    EState st = {0.f, 0.f, 0.f, 0.f, 0.f, 0.f, 0.f, 0.f};

    int p = beg;
    for (; p + 4 <= end; p += 4) {           // 4 independent gathers in flight
        uint2 r0 = csr[p], r1 = csr[p + 1], r2 = csr[p + 2], r3 = csr[p + 3];
        const __hip_bfloat16* b0 = kv + ((size_t)r0.x << 6);
        const __hip_bfloat16* b1 = kv + ((size_t)r1.x << 6);
        const __hip_bfloat16* b2 = kv + ((size_t)r2.x << 6);
        const __hip_bfloat16* b3 = kv + ((size_t)r3.x << 6);
        uint4 A0 = *(const uint4*)(b0 + 8 * h);
        uint4 A1 = *(const uint4*)(b1 + 8 * h);
        uint4 A2 = *(const uint4*)(b2 + 8 * h);
        uint4 A3 = *(const uint4*)(b3 + 8 * h);
        unsigned int B0 = *(const unsigned int*)(b0 + 40 + 2 * h);
        unsigned int B1 = *(const unsigned int*)(b1 + 40 + 2 * h);
        unsigned int B2 = *(const unsigned int*)(b2 + 40 + 2 * h);
        unsigned int B3 = *(const unsigned int*)(b3 + 40 + 2 * h);
        edge_acc(st, r0, A0, B0, qa0, qa1, qa2, qa3, qa4, qwx, qwy);
        edge_acc(st, r1, A1, B1, qa0, qa1, qa2, qa3, qa4, qwx, qwy);
        edge_acc(st, r2, A2, B2, qa0, qa1, qa2, qa3, qa4, qwx, qwy);
        edge_acc(st, r3, A3, B3, qa0, qa1, qa2, qa3, qa4, qwx, qwy);
    }
    for (; p < end; ++p) {
        uint2 r0 = csr[p];
        const __hip_bfloat16* b0 = kv + ((size_t)r0.x << 6);
        uint4 A0 = *(const uint4*)(b0 + 8 * h);
        unsigned int B0 = *(const unsigned int*)(b0 + 40 + 2 * h);
        edge_acc(st, r0, A0, B0, qa0, qa1, qa2, qa3, qa4, qwx, qwy);
    }

    float dot = 0.f;
    if (act) {
        float inv = 1.0f / (st.l + 1e-16f);
        const float* wx = &sWe[5 * h];
        const float* wy = &sWe[DD + 5 * h];
        float* ho = hout + (size_t)node * DS + 5 * h;
        float n0 = ho[0] + (st.a0 + st.Sx * wx[0] + st.Sy * wy[0]) * inv;
        float n1 = ho[1] + (st.a1 + st.Sx * wx[1] + st.Sy * wy[1]) * inv;
        float n2 = ho[2] + (st.a2 + st.Sx * wx[2] + st.Sy * wy[2]) * inv;
        float n3 = ho[3] + (st.a3 + st.Sx * wx[3] + st.Sy * wy[3]) * inv;
        float n4 = ho[4] + (st.a4 + st.Sx * wx[4] + st.Sy * wy[4]) * inv;
        ho[0] = n0; ho[1] = n1; ho[2] = n2; ho[3] = n3; ho[4] = n4;
        if (fuse_head) {
            const float* wo = &sWo[5 * h];
            dot = n0 * wo[0] + n1 * wo[1] + n2 * wo[2] + n3 * wo[3] + n4 * wo[4];
        }
    }
    if (fuse_head) {
        float dsum = dot;
#pragma unroll
        for (int k = 1; k < 5; k++) dsum += __shfl(dot, (grp * 5 + k) & 63, 64);
        if (act && h == 0) out[node] = 1.0f / (1.0f + __expf(-(dsum + sbo)));
    }
}

extern "C" void kernel_launch(void* const* d_in, const int* in_sizes, int n_in,
                              void* d_out, int out_size, void* d_ws, size_t ws_size,
                              hipStream_t stream) {
    const float* x     = (const float*)d_in[0];
    const int*   ei    = (const int*)d_in[1];     // [2,E]: src=[0..E), dst=[E..2E)
    const float* ea    = (const float*)d_in[2];   // [E,2]
    const float* Wi    = (const float*)d_in[3];
    const float* bi    = (const float*)d_in[4];
    const float* Wq    = (const float*)d_in[5];
    const float* bq    = (const float*)d_in[6];
    const float* Wk    = (const float*)d_in[7];
    const float* bk    = (const float*)d_in[8];
    const float* Wv    = (const float*)d_in[9];
    const float* bv    = (const float*)d_in[10];
    const float* We    = (const float*)d_in[11];
    const float* Wskip = (const float*)d_in[12];
    const float* bskip = (const float*)d_in[13];
    const float* Wo    = (const float*)d_in[14];
    const float* bo    = (const float*)d_in[15];
    float* out = (float*)d_out;
    (void)in_sizes; (void)n_in; (void)out_size; (void)ws_size;

    char* wsb = (char*)d_ws;
    size_t off0 = 0;
    auto alloc = [&](size_t bytes) {
        void* p = wsb + off0;
        off0 += (bytes + 127) & ~(size_t)127;
        return p;
    };
    uint2* stage  = (uint2*)alloc((size_t)NE * sizeof(uint2));               // 12.8 MB
    uint2* csr    = (uint2*)alloc((size_t)NE * sizeof(uint2));               // 12.8 MB
    __hip_bfloat16* kvrec = (__hip_bfloat16*)alloc((size_t)NN * 64 * 2);     // 12.8 MB
    __hip_bfloat16* qrec  = (__hip_bfloat16*)alloc((size_t)NN * 40 * 2);     // 8 MB
    float* hA     = (float*)alloc((size_t)NN * DS * sizeof(float));
    float* hB     = (float*)alloc((size_t)NN * DS * sizeof(float));
    int*   rowptr = (int*)alloc((size_t)(NN + 1) * sizeof(int));
    int*   cnt    = (int*)alloc((size_t)KPB * NBUK * sizeof(int));           // 640 KB
    int*   offm   = (int*)alloc((size_t)NBUK * KPB * sizeof(int));           // 640 KB
    int*   bucketTot  = (int*)alloc(NBUK * sizeof(int));
    int*   bucketBase = (int*)alloc(NBUK * sizeof(int));
    int*   dbh    = (int*)alloc((size_t)NBUK * 256 * sizeof(int));           // 200 KB
    int*   dbhE   = (int*)alloc((size_t)256 * NBUK * sizeof(int));           // 200 KB
    int*   binTot = (int*)alloc(256 * sizeof(int));
    int*   binOff = (int*)alloc(256 * sizeof(int));
    int*   perm   = (int*)alloc((size_t)NN * sizeof(int));
    uint2* begend = (uint2*)alloc((size_t)NN * sizeof(uint2));               // 800 KB

    dim3 blk(256);
    int gND = (NN * DD + 255) / 256;    // 9766

    // atomic-free CSR build + degree sort (every call — ws is re-poisoned)
    k_cnt<<<KPB, blk, 0, stream>>>(ei, cnt);
    k_cscan<<<NBUK, dim3(1024), 0, stream>>>(cnt, offm, bucketTot);
    k_bscan<<<1, blk, 0, stream>>>(bucketTot, bucketBase);
    k_part2<<<KPB, blk, 0, stream>>>(ei, ea, offm, bucketBase, stage);
    k_place<<<NBUK, dim3(512), 0, stream>>>(bucketTot, bucketBase, stage, rowptr, csr, dbh);
    k_ds<<<256, blk, 0, stream>>>(dbh, dbhE, binTot);
    k_ds2<<<1, blk, 0, stream>>>(binTot, binOff);
    k_dp<<<NBUK, dim3(512), 0, stream>>>(rowptr, dbhE, binOff, perm, begend);

    k_input_proj<<<gND, blk, 0, stream>>>(x, Wi, bi, hA);

    float* hc = hA;
    float* hn = hB;
    for (int l = 0; l < 3; l++) {
        k_qkv_skip<<<gND, blk, 0, stream>>>(hc,
                                            Wq + (size_t)l * DD * DD, bq + (size_t)l * DD,
                                            Wk + (size_t)l * DD * DD, bk + (size_t)l * DD,
                                            Wv + (size_t)l * DD * DD, bv + (size_t)l * DD,
                                            Wskip + (size_t)l * DD * DD, bskip + (size_t)l * DD,
                                            qrec, kvrec, hn);
        k_edge_fused<<<NBLK, blk, 0, stream>>>(begend, csr, perm,
                                               We + (size_t)l * EDGE_DIM * DD,
                                               qrec, kvrec, hn,
                                               (l == 2) ? 1 : 0, Wo, bo, out);
        float* t = hc; hc = hn; hn = t;
    }
}